// Round 1
// baseline (1397.703 us; speedup 1.0000x reference)
//
#include <hip/hip_runtime.h>
#include <math.h>

// Per-sample-weight MLP: 32 -> 512 -> 512 -> 512 -> 32 (silu, silu, silu, tanh)
// params layout per sample (row-major [out,in] weight, then bias):
//   W1[512x32] @0, b1[512] @16384,
//   W2[512x512] @16896, b2[512] @279040,
//   W3[512x512] @279552, b3[512] @541696,
//   W4[32x512] @542208, b4[32] @558592   (total 558624 floats)
//
// Memory-roofline problem: 1.14 GB of params streamed exactly once (~182 us at
// 6.3 TB/s). This version replaces the 64-lane wsum (6-deep swizzle chain per
// row) with 16-lane row groups: 4-step xor reduce serving 4 rows per
// instruction, h fully register-resident, and an explicit 2-deep register
// double-buffer on the W stream so 8 dwordx4 loads are always in flight.

#define BATCH  512
#define LATENT 32
#define HIDDEN 512
#define PCOUNT 558624

#define W1_OFF 0
#define B1_OFF 16384
#define W2_OFF 16896
#define B2_OFF 279040
#define W3_OFF 279552
#define B3_OFF 541696
#define W4_OFF 542208
#define B4_OFF 558592

__device__ __forceinline__ float silu_f(float x) {
    return x / (1.0f + expf(-x));
}

__device__ __forceinline__ float acc4(float4 w, float4 h, float a) {
    a = fmaf(w.x, h.x, a);
    a = fmaf(w.y, h.y, a);
    a = fmaf(w.z, h.z, a);
    a = fmaf(w.w, h.w, a);
    return a;
}

// 512->512 dense layer with silu.
// 8 waves; each wave owns 64 rows. Within a wave, 4 groups of 16 lanes each
// own one row per iteration (rows advance by 4, 16 iterations).
// h input is fully register-resident per lane (8 x float4 covering 512 via
// 16-lane group). Reduction: xor 1/2/4/8 within the 16-lane group only.
__device__ __forceinline__ void layer512(const float* __restrict__ W,
                                         const float* __restrict__ bvec,
                                         const float* __restrict__ hin,
                                         float* __restrict__ hout,
                                         int wave, int lane) {
    const int g = lane >> 4;   // row-within-quad (0..3)
    const int s = lane & 15;   // column position within 16-lane group

    // full h in registers: hv[k] = hin[k*64 + s*4 .. +3]
    float4 hv[8];
    #pragma unroll
    for (int k = 0; k < 8; ++k)
        hv[k] = *(const float4*)(hin + k * 64 + s * 4);

    const int r0 = wave * 64 + g;                 // first row for this lane
    const float* __restrict__ Wp = W + (size_t)r0 * 512 + s * 4;

    // 2-deep register double buffer on the W stream
    float4 wb[2][8];
    #pragma unroll
    for (int k = 0; k < 8; ++k)
        wb[0][k] = *(const float4*)(Wp + k * 64);

    #pragma unroll
    for (int it = 0; it < 16; ++it) {
        // prefetch next quad's row slice while this one reduces
        if (it < 15) {
            const float* __restrict__ Wn = Wp + (size_t)(it + 1) * 2048;
            #pragma unroll
            for (int k = 0; k < 8; ++k)
                wb[(it + 1) & 1][k] = *(const float4*)(Wn + k * 64);
        }
        float a0 = 0.0f, a1 = 0.0f;
        #pragma unroll
        for (int k = 0; k < 8; k += 2) {
            a0 = acc4(wb[it & 1][k],     hv[k],     a0);
            a1 = acc4(wb[it & 1][k + 1], hv[k + 1], a1);
        }
        float acc = a0 + a1;
        // 16-lane butterfly: cheapest swizzle forms, serves 4 rows at once
        acc += __shfl_xor(acc, 1);
        acc += __shfl_xor(acc, 2);
        acc += __shfl_xor(acc, 4);
        acc += __shfl_xor(acc, 8);
        if (s == 0) {
            const int o = r0 + it * 4;
            hout[o] = silu_f(acc + bvec[o]);
        }
    }
}

__global__ __launch_bounds__(512, 4) void mlp_kernel(const float* __restrict__ z,
                                                     const float* __restrict__ params,
                                                     float* __restrict__ out) {
    const int b    = blockIdx.x;
    const int tid  = threadIdx.x;
    const int wave = tid >> 6;
    const int lane = tid & 63;

    const float* __restrict__ p = params + (size_t)b * PCOUNT;

    __shared__ __align__(16) float hA[HIDDEN];
    __shared__ __align__(16) float hB[HIDDEN];

    // ---- Layer 1: 32 -> 512, silu. 8 lanes per row, 8 rows/iter, 8 iters. ----
    {
        const int j = lane & 7;   // float4 slot within a row (8 * 4 = 32)
        const int r = lane >> 3;  // row within group of 8
        float4 zin = *(const float4*)(z + b * LATENT + 4 * j);
        #pragma unroll
        for (int it = 0; it < 8; ++it) {
            int o = wave * 64 + it * 8 + r;
            float4 w = *(const float4*)(p + W1_OFF + (size_t)o * LATENT + 4 * j);
            float acc = acc4(w, zin, 0.0f);
            acc += __shfl_xor(acc, 1);
            acc += __shfl_xor(acc, 2);
            acc += __shfl_xor(acc, 4);
            if (j == 0) {
                hA[o] = silu_f(acc + p[B1_OFF + o]);
            }
        }
    }
    __syncthreads();

    // ---- Layer 2: 512 -> 512, silu ----
    layer512(p + W2_OFF, p + B2_OFF, hA, hB, wave, lane);
    __syncthreads();

    // ---- Layer 3: 512 -> 512, silu ----
    layer512(p + W3_OFF, p + B3_OFF, hB, hA, wave, lane);
    __syncthreads();

    // ---- Layer 4: 512 -> 32, tanh. 16-lane groups, 1 row per group. ----
    {
        const int g = lane >> 4;
        const int s = lane & 15;
        float4 hv[8];
        #pragma unroll
        for (int k = 0; k < 8; ++k)
            hv[k] = *(const float4*)(hA + k * 64 + s * 4);
        const int row = wave * 4 + g;
        const float* __restrict__ q = p + W4_OFF + (size_t)row * 512 + s * 4;
        float a0 = 0.0f, a1 = 0.0f;
        #pragma unroll
        for (int k = 0; k < 8; k += 2) {
            a0 = acc4(*(const float4*)(q + k * 64),       hv[k],     a0);
            a1 = acc4(*(const float4*)(q + (k + 1) * 64), hv[k + 1], a1);
        }
        float acc = a0 + a1;
        acc += __shfl_xor(acc, 1);
        acc += __shfl_xor(acc, 2);
        acc += __shfl_xor(acc, 4);
        acc += __shfl_xor(acc, 8);
        if (s == 0) {
            out[(size_t)b * LATENT + row] = tanhf(acc + p[B4_OFF + row]);
        }
    }
}

extern "C" void kernel_launch(void* const* d_in, const int* in_sizes, int n_in,
                              void* d_out, int out_size, void* d_ws, size_t ws_size,
                              hipStream_t stream) {
    // inputs: d_in[0]=t (unused scalar), d_in[1]=z [512,32] f32, d_in[2]=params [512,558624] f32
    const float* z      = (const float*)d_in[1];
    const float* params = (const float*)d_in[2];
    float* out          = (float*)d_out;
    mlp_kernel<<<BATCH, 512, 0, stream>>>(z, params, out);
}